// Round 10
// baseline (431.603 us; speedup 1.0000x reference)
//
#include <hip/hip_runtime.h>

namespace {

constexpr int T_STEPS = 1000;
constexpr int NB      = 4096;
constexpr float LOG2E = 1.4426950408889634f;

__device__ __forceinline__ float fexp2(float x) { return __builtin_amdgcn_exp2f(x); }

// Fast reciprocal on the FMA pipe (no v_rcp_f32): bit-trick seed + 2 Newton
// iterations. Rel err: seed ~6e-2 -> 3.6e-3 -> ~1.3e-5. All 2-cy VALU ops.
__device__ __forceinline__ float nrcp(float d) {
    float y = __int_as_float(0x7EF127EAu - __float_as_int(d));
    y = y * fmaf(-d, y, 2.0f);
    y = y * fmaf(-d, y, 2.0f);
    return y;
}
// sigma-hat = 1/(1+E) with E clamped so d is finite (old code relied on
// v_rcp(inf)=0; Newton needs a finite operand; 3e30 -> sigma ~3e-31 ~ 0).
__device__ __forceinline__ float sig_from(float E) {
    return nrcp(1.0f + fminf(E, 3.0e30f));
}

// DPP on the VALU pipe (R3/R6-HW-proven patterns).
template<int CTRL>
__device__ __forceinline__ float dppf(float v) {
    int i = __float_as_int(v);
    return __int_as_float(__builtin_amdgcn_update_dpp(i, i, CTRL, 0xF, 0xF, false));
}

// W=16 (R6 mapping) + in-lane L0/L1 pipelining (R8) + distance-8 slot
// prefetch (R9), with the matvecs SCALARIZED (v_fma_f32 is measured 2cy;
// v_pk_fma_f32 packed FP32 has no FLOP-rate benefit on CDNA) and all
// v_rcp_f32 replaced by FMA-pipe Newton reciprocals. v_exp_f32 kept.
__global__ __launch_bounds__(256, 1)
void lstm_fused_kernel(
    const float* __restrict__ state, const float* __restrict__ dist,
    const float* __restrict__ e1W1, const float* __restrict__ e1b1,
    const float* __restrict__ e1W2, const float* __restrict__ e1b2,
    const float* __restrict__ e2W1, const float* __restrict__ e2b1,
    const float* __restrict__ e2W2, const float* __restrict__ e2b2,
    const float* __restrict__ Wih0, const float* __restrict__ Whh0,
    const float* __restrict__ bih0, const float* __restrict__ bhh0,
    const float* __restrict__ Wih1, const float* __restrict__ Whh1,
    const float* __restrict__ bih1, const float* __restrict__ bhh1,
    const float* __restrict__ decW, const float* __restrict__ decb,
    const float* __restrict__ finW, const float* __restrict__ finb,
    const float* __restrict__ fin2W, const float* __restrict__ fin2b,
    float* __restrict__ out)
{
    const int tid = (int)threadIdx.x;
    const int q   = tid & 15;
    const int n   = blockIdx.x * 16 + (tid >> 4);
    const int u   = q & 7;
    const int hlf = q >> 3;
    const int r0  = hlf * 16 + u;   // row A (i_u | g_u)
    const int r1  = r0 + 8;         // row B (f_u | o_u)

    // probe row_ror direction once: slot k holds h[(u+sgn*k)&7]
    const int pv  = __builtin_amdgcn_update_dpp(0, q, 0x121, 0xF, 0xF, true);
    const int sgn = (pv == ((q + 1) & 15)) ? 1 : -1;
    auto pidx = [&](int k) { return (u + sgn * k) & 7; };

    const float sA   = hlf ? (-2.0f * LOG2E) : (-LOG2E);   // row A: sigmoid | tanh
    const float sB   = -LOG2E;                              // row B always sigmoid
    const float mulA = hlf ? 2.0f : 1.0f;
    const float addA = hlf ? -1.0f : 0.0f;

    // ---- scalar weight rows (h-side in the rotated slot layout) ----
    float wx0a[8], wh0a[8], wx0b[8], wh0b[8];
    float wx1a[8], wh1a[8], wx1b[8], wh1b[8];
#pragma unroll
    for (int k = 0; k < 8; ++k) {
        const int p = pidx(k);
        wx0a[k] = Wih0[r0 * 8 + k] * sA; wh0a[k] = Whh0[r0 * 8 + p] * sA;
        wx0b[k] = Wih0[r1 * 8 + k] * sB; wh0b[k] = Whh0[r1 * 8 + p] * sB;
        wx1a[k] = Wih1[r0 * 8 + p] * sA; wh1a[k] = Whh1[r0 * 8 + p] * sA;
        wx1b[k] = Wih1[r1 * 8 + p] * sB; wh1b[k] = Whh1[r1 * 8 + p] * sB;
    }
    const float bA0 = (bih0[r0] + bhh0[r0]) * sA, bB0 = (bih0[r1] + bhh0[r1]) * sB;
    const float bA1 = (bih1[r0] + bhh1[r0]) * sA, bB1 = (bih1[r1] + bhh1[r1]) * sB;

    // decoder
    const int dr = q & 3;
    float dwr[8];
#pragma unroll
    for (int k = 0; k < 8; ++k) dwr[k] = decW[dr * 8 + pidx(k)];
    const float db = decb[dr];
    float fwp[4]; float fb;
    {
        const float* Wp = (u < 4) ? finW : fin2W;
        const float* bp = (u < 4) ? finb : fin2b;
        const int oo = u & 3;
#pragma unroll
        for (int jj = 0; jj < 4; ++jj) fwp[jj] = Wp[oo * 4 + ((dr + jj) & 3)];
        fb = bp[oo];
    }

    // ---------------- x slots: issue x(0..7) loads first ----------------
    const float4* dp = reinterpret_cast<const float4*>(dist) + (size_t)n * 2;
    constexpr size_t TS4 = (size_t)NB * 2;
    float4 x0a = dp[0 * TS4], x0b = dp[0 * TS4 + 1];
    float4 x1a = dp[1 * TS4], x1b = dp[1 * TS4 + 1];
    float4 x2a = dp[2 * TS4], x2b = dp[2 * TS4 + 1];
    float4 x3a = dp[3 * TS4], x3b = dp[3 * TS4 + 1];
    float4 x4a = dp[4 * TS4], x4b = dp[4 * TS4 + 1];
    float4 x5a = dp[5 * TS4], x5b = dp[5 * TS4 + 1];
    float4 x6a = dp[6 * TS4], x6b = dp[6 * TS4 + 1];
    float4 x7a = dp[7 * TS4], x7b = dp[7 * TS4 + 1];

    // ---------------- encoders (overlaps the loads) ----------------
    float hE[8], hO[8], h1v[8];   // h0 even/odd ping-pong, h1 state
    float c0, c1;
    {
        float s[16];
#pragma unroll
        for (int k = 0; k < 16; ++k) s[k] = state[n * 16 + k];
        float hm1[4], hm2[4];
#pragma unroll
        for (int m = 0; m < 4; ++m) {
            float a = e1b1[m], b = e2b1[m];
#pragma unroll
            for (int k = 0; k < 16; ++k) {
                a = fmaf(s[k], e1W1[m * 16 + k], a);
                b = fmaf(s[k], e2W1[m * 16 + k], b);
            }
            hm1[m] = fmaxf(a, 0.0f); hm2[m] = fmaxf(b, 0.0f);
        }
#pragma unroll
        for (int k = 0; k < 8; ++k) {
            const int p = pidx(k);
            float a = e1b2[p], b = e1b2[8 + p];
#pragma unroll
            for (int m = 0; m < 4; ++m) {
                a = fmaf(hm1[m], e1W2[p * 4 + m], a);
                b = fmaf(hm1[m], e1W2[(8 + p) * 4 + m], b);
            }
            hO[k] = fmaxf(a, 0.0f);   // h0 init (slot layout)
            hE[k] = hO[k];
            h1v[k] = fmaxf(b, 0.0f);  // h1 init
        }
        float a = e2b2[u], b = e2b2[8 + u];
#pragma unroll
        for (int m = 0; m < 4; ++m) {
            a = fmaf(hm2[m], e2W2[u * 4 + m], a);
            b = fmaf(hm2[m], e2W2[(8 + u) * 4 + m], b);
        }
        c0 = fmaxf(a, 0.0f);
        c1 = fmaxf(b, 0.0f);
    }

    float* outp = out + ((u < 4) ? ((size_t)n * 4 + u)
                                 : ((size_t)T_STEPS * NB * 4 + (size_t)n * 4 + (u - 4)));
    const bool doStore = (q < 8);

    // L0(t): x(t) + h0(t-1) [R] -> h0(t) [W]. Scalar 2-way-split chains.
    auto L0body = [&](const float4& lo, const float4& hi,
                      const float (&R)[8], float (&W)[8]) {
        const float x[8] = {lo.x, lo.y, lo.z, lo.w, hi.x, hi.y, hi.z, hi.w};
        float xa0 = bA0, xa1 = 0.0f, ha0 = 0.0f, ha1 = 0.0f;
        float xb0 = bB0, xb1 = 0.0f, hb0 = 0.0f, hb1 = 0.0f;
#pragma unroll
        for (int k = 0; k < 4; ++k) {
            xa0 = fmaf(x[k],     wx0a[k],     xa0);
            xa1 = fmaf(x[4 + k], wx0a[4 + k], xa1);
            ha0 = fmaf(R[k],     wh0a[k],     ha0);
            ha1 = fmaf(R[4 + k], wh0a[4 + k], ha1);
            xb0 = fmaf(x[k],     wx0b[k],     xb0);
            xb1 = fmaf(x[4 + k], wx0b[4 + k], xb1);
            hb0 = fmaf(R[k],     wh0b[k],     hb0);
            hb1 = fmaf(R[4 + k], wh0b[4 + k], hb1);
        }
        const float A = (xa0 + xa1) + (ha0 + ha1);
        const float B = (xb0 + xb1) + (hb0 + hb1);
        float a0 = fmaf(sig_from(fexp2(A)), mulA, addA);  // sig(i)|tanh(g)
        float a1 = sig_from(fexp2(B));                     // sig(f)|sig(o)
        const float s0 = dppf<0x128>(a0);
        const float s1 = dppf<0x128>(a1);
        const float prod = a0 * s0;
        const float fg = hlf ? s1 : a1;
        const float og = hlf ? a1 : s1;
        c0 = fmaf(fg, c0, prod);
        const float rr  = sig_from(fexp2(c0 * (-2.0f * LOG2E)));
        const float og2 = og + og;
        const float hn  = fmaf(og2, rr, -og);              // og * tanh(c0)
        W[0] = hn;
        W[1] = dppf<0x121>(hn); W[2] = dppf<0x122>(hn); W[3] = dppf<0x123>(hn);
        W[4] = dppf<0x124>(hn); W[5] = dppf<0x125>(hn); W[6] = dppf<0x126>(hn);
        W[7] = dppf<0x127>(hn);
    };

    // L1(t-1)+dec+store: consumes h0(t-1) [R] + h1 state in place.
    auto L1decBody = [&](const float (&R)[8], float* op) {
        float xa0 = bA1, xa1 = 0.0f, ha0 = 0.0f, ha1 = 0.0f;
        float xb0 = bB1, xb1 = 0.0f, hb0 = 0.0f, hb1 = 0.0f;
#pragma unroll
        for (int k = 0; k < 4; ++k) {
            xa0 = fmaf(R[k],       wx1a[k],     xa0);
            xa1 = fmaf(R[4 + k],   wx1a[4 + k], xa1);
            ha0 = fmaf(h1v[k],     wh1a[k],     ha0);
            ha1 = fmaf(h1v[4 + k], wh1a[4 + k], ha1);
            xb0 = fmaf(R[k],       wx1b[k],     xb0);
            xb1 = fmaf(R[4 + k],   wx1b[4 + k], xb1);
            hb0 = fmaf(h1v[k],     wh1b[k],     hb0);
            hb1 = fmaf(h1v[4 + k], wh1b[4 + k], hb1);
        }
        const float A = (xa0 + xa1) + (ha0 + ha1);
        const float B = (xb0 + xb1) + (hb0 + hb1);
        float a0 = fmaf(sig_from(fexp2(A)), mulA, addA);
        float a1 = sig_from(fexp2(B));
        const float s0 = dppf<0x128>(a0);
        const float s1 = dppf<0x128>(a1);
        const float prod = a0 * s0;
        const float fg = hlf ? s1 : a1;
        const float og = hlf ? a1 : s1;
        c1 = fmaf(fg, c1, prod);
        const float rr  = sig_from(fexp2(c1 * (-2.0f * LOG2E)));
        const float og2 = og + og;
        const float hn  = fmaf(og2, rr, -og);
        h1v[0] = hn;
        h1v[1] = dppf<0x121>(hn); h1v[2] = dppf<0x122>(hn); h1v[3] = dppf<0x123>(hn);
        h1v[4] = dppf<0x124>(hn); h1v[5] = dppf<0x125>(hn); h1v[6] = dppf<0x126>(hn);
        h1v[7] = dppf<0x127>(hn);
        // decoder + heads on fresh h1
        float da0 = db, da1 = 0.0f;
#pragma unroll
        for (int k = 0; k < 4; ++k) {
            da0 = fmaf(h1v[k],     dwr[k],     da0);
            da1 = fmaf(h1v[4 + k], dwr[4 + k], da1);
        }
        float da = fmaxf(da0 + da1, 0.0f);
        const float d1 = dppf<0x39>(da);
        const float d2 = dppf<0x4E>(da);
        const float d3 = dppf<0x93>(da);
        float o = fb;
        o = fmaf(da, fwp[0], o); o = fmaf(d1, fwp[1], o);
        o = fmaf(d2, fwp[2], o); o = fmaf(d3, fwp[3], o);
        if (doStore) *op = o;
    };

    // consume slot, reload SAME slot with x(t+8), then L1(t-1)+dec+store.
#define SUBSTEP(XA, XB, R, W, LP)                                         \
    L0body(XA, XB, R, W);                                                 \
    XA = (LP)[0]; XB = (LP)[1];                                           \
    L1decBody(R, outp); outp += (size_t)NB * 4;

#define SUBTAIL(XA, XB, R, W)                                             \
    L0body(XA, XB, R, W);                                                 \
    L1decBody(R, outp); outp += (size_t)NB * 4;

    // prologue: t=0 (even): L0 only; slot0 reloads x8.
    L0body(x0a, x0b, hO, hE);
    x0a = dp[8 * TS4]; x0b = dp[8 * TS4 + 1];

    // main: k=0..123, sub-step i handles t=8k+1+i, loads x(t+8).
    const float4* pf = dp + 9 * TS4;
    for (int k = 0; k < 124; ++k) {
        const float4* pb = pf;
        const float4* p7 = (k == 123) ? dp : (pb + 7 * TS4);  // clamp x(1000)
        SUBSTEP(x1a, x1b, hE, hO, pb + 0 * TS4)   // t odd
        SUBSTEP(x2a, x2b, hO, hE, pb + 1 * TS4)   // t even
        SUBSTEP(x3a, x3b, hE, hO, pb + 2 * TS4)
        SUBSTEP(x4a, x4b, hO, hE, pb + 3 * TS4)
        SUBSTEP(x5a, x5b, hE, hO, pb + 4 * TS4)
        SUBSTEP(x6a, x6b, hO, hE, pb + 5 * TS4)
        SUBSTEP(x7a, x7b, hE, hO, pb + 6 * TS4)
        SUBSTEP(x0a, x0b, hO, hE, p7)             // t=8k+8
        pf += 8 * TS4;
    }
    // tail: t=993..999 (slots already loaded; no more loads)
    SUBTAIL(x1a, x1b, hE, hO)   // 993
    SUBTAIL(x2a, x2b, hO, hE)   // 994
    SUBTAIL(x3a, x3b, hE, hO)   // 995
    SUBTAIL(x4a, x4b, hO, hE)   // 996
    SUBTAIL(x5a, x5b, hE, hO)   // 997
    SUBTAIL(x6a, x6b, hO, hE)   // 998
    SUBTAIL(x7a, x7b, hE, hO)   // 999
    // epilogue: L1(999)+dec+store (h0(999) sits in hO)
    L1decBody(hO, outp);

#undef SUBSTEP
#undef SUBTAIL
}

} // namespace

extern "C" void kernel_launch(void* const* d_in, const int* in_sizes, int n_in,
                              void* d_out, int out_size, void* d_ws, size_t ws_size,
                              hipStream_t stream) {
    const float* state = (const float*)d_in[0];
    const float* dist  = (const float*)d_in[1];
    const float* e1W1  = (const float*)d_in[2];
    const float* e1b1  = (const float*)d_in[3];
    const float* e1W2  = (const float*)d_in[4];
    const float* e1b2  = (const float*)d_in[5];
    const float* e2W1  = (const float*)d_in[6];
    const float* e2b1  = (const float*)d_in[7];
    const float* e2W2  = (const float*)d_in[8];
    const float* e2b2  = (const float*)d_in[9];
    const float* Wih0  = (const float*)d_in[10];
    const float* Whh0  = (const float*)d_in[11];
    const float* bih0  = (const float*)d_in[12];
    const float* bhh0  = (const float*)d_in[13];
    const float* Wih1  = (const float*)d_in[14];
    const float* Whh1  = (const float*)d_in[15];
    const float* bih1  = (const float*)d_in[16];
    const float* bhh1  = (const float*)d_in[17];
    const float* decW  = (const float*)d_in[18];
    const float* decb  = (const float*)d_in[19];
    const float* finW  = (const float*)d_in[20];
    const float* finb  = (const float*)d_in[21];
    const float* fin2W = (const float*)d_in[22];
    const float* fin2b = (const float*)d_in[23];
    float* outp = (float*)d_out;

    lstm_fused_kernel<<<dim3(NB / 16), dim3(256), 0, stream>>>(
        state, dist,
        e1W1, e1b1, e1W2, e1b2,
        e2W1, e2b1, e2W2, e2b2,
        Wih0, Whh0, bih0, bhh0,
        Wih1, Whh1, bih1, bhh1,
        decW, decb, finW, finb, fin2W, fin2b,
        outp);
}